// Round 7
// baseline (922.252 us; speedup 1.0000x reference)
//
#include <hip/hip_runtime.h>

// (B, N, D, H) = (8, 4096, 256, 8), PS=8 -> image 64x64; blocked m=fine pos, n=tile idx.
// SPEC FACT 1: no softmax temperature; logit sigma ~16. f16 inputs + fp32 MFMA acc -> logit err ~0.01 (safe).
// SPEC FACT 2: Z = einsum('bhmnd,hdv->bmnd', O, o) is DIAGONAL in d, SUMS v:
//   Z[...,d] = sum_h O_h[...,d] * os[h][d], os[h][d] = sum_v o[h,d,v].
// SPEC FACT 3: S = a M_h a^T with M_h = q_h k^T (256x256/head, precomputed fp32 -> f16).
// MFMA conventions (verified r6, absmax 0.125): mfma_f32_16x16x32_f16 computing C = A @ B^T:
//   A-frag: A[m = tile*16 + (lane&15)][k = (lane>>4)*8 + j]; B-frag same with n-rows;
//   C/D: col = tile*16 + (lane&15), row = tile*16 + (lane>>4)*4 + reg.
#define Bc   8
#define Tc   4096
#define Dc   256
#define EPSc 1e-5f
#define WST  268   // shW row stride (halves): 4-row quad offset = 536dw = 24 mod 32 -> distinct octets

typedef _Float16 half_t;
typedef __attribute__((ext_vector_type(4))) _Float16 half4_t;
typedef __attribute__((ext_vector_type(8))) _Float16 frag8;
typedef __attribute__((ext_vector_type(4))) float f32x4;

#define MFMA_F16(a, b, c) __builtin_amdgcn_mfma_f32_16x16x32_f16((a), (b), (c), 0, 0, 0)

__device__ __forceinline__ frag8 ld_frag8_lds(const half_t* p) {  // 8B-aligned safe
  half4_t lo = *(const half4_t*)p, hi = *(const half4_t*)(p + 4);
  frag8 f;
  f[0] = lo[0]; f[1] = lo[1]; f[2] = lo[2]; f[3] = lo[3];
  f[4] = hi[0]; f[5] = hi[1]; f[6] = hi[2]; f[7] = hi[3];
  return f;
}

// ---------------- os[h][d] = sum_v o[h,d,v] ----------------
__global__ __launch_bounds__(256) void osum_kernel(const float* __restrict__ o, float* __restrict__ os) {
  int h = blockIdx.x, d = threadIdx.x;
  const float* row = o + ((size_t)h * 256 + d) * 256;
  float s = 0.f;
  #pragma unroll 8
  for (int v = 0; v < 256; v += 4) {
    float4 r4 = *(const float4*)&row[v];
    s += r4.x + r4.y + r4.z + r4.w;
  }
  os[h * 256 + d] = s;
}

// ---------------- Mt[h][e][d] = M_h[d][e] = sum_i q[h][d][i]*k[e][i]  (f16) ----------------
__global__ __launch_bounds__(256) void prepM_kernel(const float* __restrict__ q,
                                                    const float* __restrict__ k,
                                                    half_t* __restrict__ Mt) {
  __shared__ float shK[64 * 256];
  int h = blockIdx.x >> 2, et = blockIdx.x & 3;
  int tid = threadIdx.x;   // = d
  for (int i = 0; i < 64; i++) shK[i * 256 + tid] = k[(size_t)(et * 64 + i) * 256 + tid];
  __syncthreads();
  const float* qr = q + ((size_t)h * 256 + tid) * 256;
  float acc[64];
  #pragma unroll
  for (int e = 0; e < 64; e++) acc[e] = 0.f;
  for (int i0 = 0; i0 < 256; i0 += 4) {
    float4 qv = *(const float4*)&qr[i0];
    #pragma unroll
    for (int e = 0; e < 64; e++) {
      float4 kv = *(const float4*)&shK[e * 256 + i0];
      acc[e] += qv.x * kv.x + qv.y * kv.y + qv.z * kv.z + qv.w * kv.w;
    }
  }
  for (int e = 0; e < 64; e++)
    Mt[((size_t)h * 256 + et * 64 + e) * 256 + tid] = (half_t)acc[e];
}

// ---------------- transpose v/w1/w2 -> f16 [n][d] ----------------
__global__ __launch_bounds__(256) void prepT_kernel(const float* __restrict__ v,
                                                    const float* __restrict__ w1,
                                                    const float* __restrict__ w2,
                                                    half_t* vt, half_t* w1t, half_t* w2t) {
  int which = blockIdx.x >> 8, n = blockIdx.x & 255, d = threadIdx.x;
  const float* src = which == 0 ? v : (which == 1 ? w1 : w2);
  half_t* dst = which == 0 ? vt : (which == 1 ? w1t : w2t);
  dst[(size_t)n * 256 + d] = (half_t)src[(size_t)d * 256 + n];
}

// ---------------- LN1 + blocked permute -> f16; one wave per row ----------------
__global__ __launch_bounds__(256) void ln1_kernel(
    const float* __restrict__ x, const float* __restrict__ w,
    const float* __restrict__ bia, half_t* __restrict__ aH) {
  int row  = blockIdx.x * 4 + (threadIdx.x >> 6);
  int lane = threadIdx.x & 63;
  float4 v = *(const float4*)&x[(size_t)row * 256 + lane * 4];
  float s  = v.x + v.y + v.z + v.w;
  float sq = v.x * v.x + v.y * v.y + v.z * v.z + v.w * v.w;
  #pragma unroll
  for (int off = 1; off < 64; off <<= 1) { s += __shfl_xor(s, off); sq += __shfl_xor(sq, off); }
  float mean = s * (1.f / 256), var = sq * (1.f / 256) - mean * mean;
  float r = rsqrtf(var + EPSc);
  float4 wv = *(const float4*)&w[lane * 4];
  float4 bv = *(const float4*)&bia[lane * 4];
  half4_t y;
  y[0] = (half_t)((v.x - mean) * r * wv.x + bv.x);
  y[1] = (half_t)((v.y - mean) * r * wv.y + bv.y);
  y[2] = (half_t)((v.z - mean) * r * wv.z + bv.z);
  y[3] = (half_t)((v.w - mean) * r * wv.w + bv.w);
  int bb = row >> 12, p = row & 4095, hh = p >> 6, ww = p & 63;
  int m = (hh & 7) * 8 + (ww & 7), n = (hh >> 3) * 8 + (ww >> 3);
  *(half4_t*)&aH[((size_t)((bb * 64 + m) * 64 + n)) * 256 + lane * 4] = y;
}

// ---------------- generic MFMA GEMM: 32 rows x 256 cols, K=256 (fc1/fc2) ----------------
// epi 1: +bias, relu -> f16. epi 2: +bias, +resid -> fp32.
__global__ __launch_bounds__(256) void gemm_kernel(
    const half_t* __restrict__ A, const half_t* __restrict__ Bt,
    const float* __restrict__ bias, float* __restrict__ outf,
    half_t* __restrict__ outh, int epi) {
  __shared__ half_t shA[32 * 264];   // 16.9 KB
  int tid = threadIdx.x, lane = tid & 63, wave = tid >> 6;
  int l16 = lane & 15, quad = lane >> 4;
  int r0 = blockIdx.x * 32;
  for (int it = 0; it < 8; it++) {
    int e = it * 1024 + tid * 4; int z = e >> 8, col = e & 255;
    *(half4_t*)&shA[z * 264 + col] = *(const half4_t*)&A[(size_t)(r0 + z) * 256 + col];
  }
  __syncthreads();
  f32x4 acc[2][4];
  #pragma unroll
  for (int mt = 0; mt < 2; mt++)
    #pragma unroll
    for (int nt = 0; nt < 4; nt++) acc[mt][nt] = (f32x4){0.f, 0.f, 0.f, 0.f};
  for (int ks = 0; ks < 8; ks++) {
    int k0 = ks * 32 + quad * 8;
    frag8 af[2], bf[4];
    #pragma unroll
    for (int mt = 0; mt < 2; mt++) af[mt] = *(const frag8*)&shA[(mt * 16 + l16) * 264 + k0];
    #pragma unroll
    for (int nt = 0; nt < 4; nt++) bf[nt] = *(const frag8*)&Bt[(size_t)(wave * 64 + nt * 16 + l16) * 256 + k0];
    #pragma unroll
    for (int mt = 0; mt < 2; mt++)
      #pragma unroll
      for (int nt = 0; nt < 4; nt++) acc[mt][nt] = MFMA_F16(af[mt], bf[nt], acc[mt][nt]);
  }
  #pragma unroll
  for (int mt = 0; mt < 2; mt++)
    #pragma unroll
    for (int nt = 0; nt < 4; nt++)
      #pragma unroll
      for (int r = 0; r < 4; r++) {
        int row = r0 + mt * 16 + quad * 4 + r;
        int col = wave * 64 + nt * 16 + l16;
        float vv = acc[mt][nt][r] + bias[col];
        if (epi == 1) vv = fmaxf(vv, 0.f);
        size_t idx = (size_t)row * 256 + col;
        if (epi == 2) outf[idx] = vv + outf[idx];
        else          outh[idx] = (half_t)vv;
      }
}

// ---------------- VT gemm: VT[g][d][m] = sum_e v[e][d] * A_g[m][e]  (per-group transposed V) ----------------
// mode 0: group (b, n=slice), key rows over m.  mode 1: group (b, m=slice), key rows over n.
__global__ __launch_bounds__(256) void vtrans_kernel(
    const half_t* __restrict__ aH, const half_t* __restrict__ vt,
    half_t* __restrict__ VT, int mode) {
  int tid = threadIdx.x, lane = tid & 63, wave = tid >> 6;
  int l16 = lane & 15, quad = lane >> 4;
  int g = blockIdx.x, b = g >> 6, slice = g & 63;
  f32x4 acc[4][4];
  #pragma unroll
  for (int j = 0; j < 4; j++)
    #pragma unroll
    for (int mt = 0; mt < 4; mt++) acc[j][mt] = (f32x4){0.f, 0.f, 0.f, 0.f};
  for (int ks = 0; ks < 8; ks++) {
    int k0 = ks * 32 + quad * 8;
    frag8 af[4], bf[4];
    #pragma unroll
    for (int j = 0; j < 4; j++)
      af[j] = *(const frag8*)&vt[(size_t)(wave * 64 + j * 16 + l16) * 256 + k0];
    #pragma unroll
    for (int mt = 0; mt < 4; mt++) {
      int mrow = mt * 16 + l16;
      size_t br = mode ? ((size_t)(b * 64 + slice) * 64 + mrow)
                       : ((size_t)(b * 64 + mrow) * 64 + slice);
      bf[mt] = *(const frag8*)&aH[br * 256 + k0];
    }
    #pragma unroll
    for (int j = 0; j < 4; j++)
      #pragma unroll
      for (int mt = 0; mt < 4; mt++) acc[j][mt] = MFMA_F16(af[j], bf[mt], acc[j][mt]);
  }
  half_t* out = VT + (size_t)g * 16384;
  #pragma unroll
  for (int j = 0; j < 4; j++)
    #pragma unroll
    for (int mt = 0; mt < 4; mt++)
      #pragma unroll
      for (int r = 0; r < 4; r++) {
        int d = wave * 64 + j * 16 + quad * 4 + r;
        int m = mt * 16 + l16;
        out[(size_t)d * 64 + m] = (half_t)acc[j][mt][r];
      }
}

// ---------------- score: one (group, head) per block. W = A_g @ M_h -> S = W @ A_g^T -> softmax -> P ----
__global__ __launch_bounds__(256) void attn_score_kernel(
    const half_t* __restrict__ aH, const half_t* __restrict__ Mt,
    half_t* __restrict__ P, int mode) {
  __shared__ half_t shW[64 * WST];   // 33.5 KB
  int tid = threadIdx.x, lane = tid & 63, wave = tid >> 6;
  int l16 = lane & 15, quad = lane >> 4;
  int gh = blockIdx.x, g = gh >> 2, hh = gh & 3;
  int b = g >> 6, slice = g & 63;
  int h = (mode ? 4 : 0) + hh;
  const half_t* mth = Mt + (size_t)h * 65536;

  // --- GEMM1: W (wave's 16 rows x 256 e-cols) ---
  {
    size_t arow = mode ? ((size_t)(b * 64 + slice) * 64 + wave * 16 + l16)
                       : ((size_t)(b * 64 + wave * 16 + l16) * 64 + slice);
    const half_t* ap = aH + arow * 256;
    frag8 af[8];
    #pragma unroll
    for (int ks = 0; ks < 8; ks++) af[ks] = *(const frag8*)&ap[ks * 32 + quad * 8];
    f32x4 wacc[16];
    #pragma unroll
    for (int nt = 0; nt < 16; nt++) wacc[nt] = (f32x4){0.f, 0.f, 0.f, 0.f};
    for (int ks = 0; ks < 8; ks++) {
      int k0 = ks * 32 + quad * 8;
      #pragma unroll
      for (int nt = 0; nt < 16; nt++) {
        frag8 bf = *(const frag8*)&mth[(size_t)(nt * 16 + l16) * 256 + k0];
        wacc[nt] = MFMA_F16(af[ks], bf, wacc[nt]);
      }
    }
    #pragma unroll
    for (int nt = 0; nt < 16; nt++)
      #pragma unroll
      for (int r = 0; r < 4; r++)
        shW[(wave * 16 + quad * 4 + r) * WST + nt * 16 + l16] = (half_t)wacc[nt][r];
  }
  __syncthreads();
  // --- GEMM2: S (wave's 16 rows x 64 z) = W @ A_g^T ---
  f32x4 sacc[4];
  #pragma unroll
  for (int nt = 0; nt < 4; nt++) sacc[nt] = (f32x4){0.f, 0.f, 0.f, 0.f};
  for (int ks = 0; ks < 8; ks++) {
    int k0 = ks * 32 + quad * 8;
    frag8 wf = ld_frag8_lds(&shW[(wave * 16 + l16) * WST + k0]);
    #pragma unroll
    for (int nt = 0; nt < 4; nt++) {
      int z = nt * 16 + l16;
      size_t br = mode ? ((size_t)(b * 64 + slice) * 64 + z)
                       : ((size_t)(b * 64 + z) * 64 + slice);
      frag8 kf = *(const frag8*)&aH[br * 256 + k0];
      sacc[nt] = MFMA_F16(wf, kf, sacc[nt]);
    }
  }
  // --- softmax over 64 z (4 accs x 16 lanes of the quad), write P ---
  half_t* pb = P + (size_t)gh * 4096;
  #pragma unroll
  for (int r = 0; r < 4; r++) {
    float mx = fmaxf(fmaxf(sacc[0][r], sacc[1][r]), fmaxf(sacc[2][r], sacc[3][r]));
    #pragma unroll
    for (int off = 1; off < 16; off <<= 1) mx = fmaxf(mx, __shfl_xor(mx, off));
    float e0 = __expf(sacc[0][r] - mx), e1 = __expf(sacc[1][r] - mx);
    float e2 = __expf(sacc[2][r] - mx), e3 = __expf(sacc[3][r] - mx);
    float sum = e0 + e1 + e2 + e3;
    #pragma unroll
    for (int off = 1; off < 16; off <<= 1) sum += __shfl_xor(sum, off);
    float inv = 1.f / sum;
    size_t prow = (size_t)(wave * 16 + quad * 4 + r) * 64 + l16;
    pb[prow +  0] = (half_t)(e0 * inv);
    pb[prow + 16] = (half_t)(e1 * inv);
    pb[prow + 32] = (half_t)(e2 * inv);
    pb[prow + 48] = (half_t)(e3 * inv);
  }
}

// ---------------- pv: one (group, m-quarter) per block, LDS-free. Z (+)= (P @ V) * os[h] ----------------
__global__ __launch_bounds__(256) void attn_pv_kernel(
    const half_t* __restrict__ P, const half_t* __restrict__ VT,
    const float* __restrict__ osum, half_t* __restrict__ Z, int mode) {
  int tid = threadIdx.x, lane = tid & 63, wave = tid >> 6;
  int l16 = lane & 15, quad = lane >> 4;
  int g = blockIdx.x >> 2, mq = blockIdx.x & 3;
  int b = g >> 6, slice = g & 63;
  const half_t* vtg = VT + (size_t)g * 16384;
  f32x4 zacc[4];
  #pragma unroll
  for (int j = 0; j < 4; j++) zacc[j] = (f32x4){0.f, 0.f, 0.f, 0.f};
  int hbase = mode ? 4 : 0;
  for (int hh = 0; hh < 4; hh++) {
    const half_t* ph = P + ((size_t)(g * 4 + hh)) * 4096;
    f32x4 oacc[4];
    #pragma unroll
    for (int j = 0; j < 4; j++) oacc[j] = (f32x4){0.f, 0.f, 0.f, 0.f};
    #pragma unroll
    for (int ks = 0; ks < 2; ks++) {
      int k0 = ks * 32 + quad * 8;
      frag8 pf = *(const frag8*)&ph[(size_t)(mq * 16 + l16) * 64 + k0];
      #pragma unroll
      for (int j = 0; j < 4; j++) {
        int d = (wave * 4 + j) * 16 + l16;
        frag8 vf = *(const frag8*)&vtg[(size_t)d * 64 + k0];
        oacc[j] = MFMA_F16(pf, vf, oacc[j]);
      }
    }
    #pragma unroll
    for (int j = 0; j < 4; j++) {
      float osv = osum[(hbase + hh) * 256 + (wave * 4 + j) * 16 + l16];
      #pragma unroll
      for (int r = 0; r < 4; r++) zacc[j][r] += oacc[j][r] * osv;
    }
  }
  // token-space store (un-permute folded); mode0 '=', mode1 '+='
  #pragma unroll
  for (int j = 0; j < 4; j++) {
    int d = (wave * 4 + j) * 16 + l16;
    #pragma unroll
    for (int r = 0; r < 4; r++) {
      int grow = mq * 16 + quad * 4 + r;
      int mm = mode ? slice : grow;
      int nn = mode ? grow : slice;
      int himg = (nn >> 3) * 8 + (mm >> 3), wimg = (nn & 7) * 8 + (mm & 7);
      size_t zi = ((size_t)(b * 4096 + himg * 64 + wimg)) * 256 + d;
      if (mode) Z[zi] = (half_t)((float)Z[zi] + zacc[j][r]);
      else      Z[zi] = (half_t)zacc[j][r];
    }
  }
}

// ---------------- residual + LN2; x2 -> d_out fp32, h -> f16 ----------------
__global__ __launch_bounds__(256) void ln2_kernel(
    const float* __restrict__ x, const half_t* __restrict__ Z,
    const float* __restrict__ w, const float* __restrict__ bia,
    float* __restrict__ x2out, half_t* __restrict__ hH) {
  int row  = blockIdx.x * 4 + (threadIdx.x >> 6);
  int lane = threadIdx.x & 63;
  size_t base = (size_t)row * 256 + lane * 4;
  float4 xv = *(const float4*)&x[base];
  half4_t zv = *(const half4_t*)&Z[base];
  float4 v;
  v.x = xv.x + (float)zv[0]; v.y = xv.y + (float)zv[1];
  v.z = xv.z + (float)zv[2]; v.w = xv.w + (float)zv[3];
  float s  = v.x + v.y + v.z + v.w;
  float sq = v.x * v.x + v.y * v.y + v.z * v.z + v.w * v.w;
  #pragma unroll
  for (int off = 1; off < 64; off <<= 1) { s += __shfl_xor(s, off); sq += __shfl_xor(sq, off); }
  float mean = s * (1.f / 256), var = sq * (1.f / 256) - mean * mean;
  float r = rsqrtf(var + EPSc);
  float4 wv = *(const float4*)&w[lane * 4];
  float4 bv = *(const float4*)&bia[lane * 4];
  *(float4*)&x2out[base] = v;
  half4_t y;
  y[0] = (half_t)((v.x - mean) * r * wv.x + bv.x);
  y[1] = (half_t)((v.y - mean) * r * wv.y + bv.y);
  y[2] = (half_t)((v.z - mean) * r * wv.z + bv.z);
  y[3] = (half_t)((v.w - mean) * r * wv.w + bv.w);
  *(half4_t*)&hH[base] = y;
}

extern "C" void kernel_launch(void* const* d_in, const int* in_sizes, int n_in,
                              void* d_out, int out_size, void* d_ws, size_t ws_size,
                              hipStream_t stream) {
  (void)in_sizes; (void)n_in; (void)out_size; (void)ws_size;
  const float* x    = (const float*)d_in[0];
  const float* ln1w = (const float*)d_in[1];
  const float* ln1b = (const float*)d_in[2];
  const float* q    = (const float*)d_in[3];
  const float* k    = (const float*)d_in[4];
  const float* v    = (const float*)d_in[5];
  const float* o    = (const float*)d_in[6];
  const float* ln2w = (const float*)d_in[7];
  const float* ln2b = (const float*)d_in[8];
  const float* w1   = (const float*)d_in[9];
  const float* b1   = (const float*)d_in[10];
  const float* w2   = (const float*)d_in[11];
  const float* b2   = (const float*)d_in[12];
  float* out = (float*)d_out;

  const size_t ROWS = (size_t)Bc * Tc;        // 32768
  const size_t ELTS = ROWS * Dc;              // 8,388,608
  const size_t MB16 = ELTS * sizeof(half_t);  // 16 MiB
  // ws plan (82 MiB; ws >= ~112 MiB established r1-r3):
  //   [0:8K) os | [64K:1M+64K) Mt | then vt/w1t/w2t (128K each)
  //   [2M:18M)   aH f16 (blocked)    -> reused as hH after attention
  //   [18M:34M)  VT0 f16 (per-group V^T, mode0)  -> reused as tH after ln2
  //   [34M:50M)  VT1 f16 (mode1)
  //   [50M:66M)  Z f16 (token space)
  //   [66M:82M)  P f16 (per-mode scratch)
  char* ws = (char*)d_ws;
  float*  osumB = (float*)ws;
  half_t* Mt    = (half_t*)(ws + (64 << 10));
  half_t* vt    = (half_t*)(ws + (64 << 10) + (1 << 20));
  half_t* w1t   = (half_t*)(ws + (64 << 10) + (1 << 20) + (128 << 10));
  half_t* w2t   = (half_t*)(ws + (64 << 10) + (1 << 20) + (256 << 10));
  half_t* aH    = (half_t*)(ws + (2 << 20));
  half_t* VT0   = (half_t*)(ws + (2 << 20) + MB16);
  half_t* VT1   = (half_t*)(ws + (2 << 20) + 2 * MB16);
  half_t* Zb    = (half_t*)(ws + (2 << 20) + 3 * MB16);
  half_t* Pb    = (half_t*)(ws + (2 << 20) + 4 * MB16);
  half_t* hH    = aH;    // reuse (a dead after attention)
  half_t* tH    = VT0;   // reuse (VT0 dead after pv0)

  osum_kernel <<<8,   256, 0, stream>>>(o, osumB);
  prepM_kernel<<<32,  256, 0, stream>>>(q, k, Mt);
  prepT_kernel<<<768, 256, 0, stream>>>(v, w1, w2, vt, w1t, w2t);
  ln1_kernel  <<<ROWS / 4, 256, 0, stream>>>(x, ln1w, ln1b, aH);
  // per-group transposed V (replaces V projection + per-block LDS transpose)
  vtrans_kernel<<<512, 256, 0, stream>>>(aH, vt, VT0, 0);
  vtrans_kernel<<<512, 256, 0, stream>>>(aH, vt, VT1, 1);
  // attention: scores+softmax then PV, per mode (mode0 '=', mode1 '+=')
  attn_score_kernel<<<2048, 256, 0, stream>>>(aH, Mt, Pb, 0);
  attn_pv_kernel   <<<2048, 256, 0, stream>>>(Pb, VT0, osumB, Zb, 0);
  attn_score_kernel<<<2048, 256, 0, stream>>>(aH, Mt, Pb, 1);
  attn_pv_kernel   <<<2048, 256, 0, stream>>>(Pb, VT1, osumB, Zb, 1);
  // residual + LN2
  ln2_kernel  <<<ROWS / 4, 256, 0, stream>>>(x, Zb, ln2w, ln2b, out, hH);
  // MLP (32-row blocks for occupancy): fc1 relu -> tH; fc2 +bias +resid -> out
  gemm_kernel <<<ROWS / 32, 256, 0, stream>>>(hH, w1t, b1, nullptr, tH, 1);
  gemm_kernel <<<ROWS / 32, 256, 0, stream>>>(tH, w2t, b2, out, nullptr, 2);
}

// Round 8
// 751.966 us; speedup vs baseline: 1.2265x; 1.2265x over previous
//
#include <hip/hip_runtime.h>

// (B, N, D, H) = (8, 4096, 256, 8), PS=8 -> image 64x64; blocked m=fine pos, n=tile idx.
// SPEC FACT 1: no softmax temperature; logit sigma ~16. f16 inputs + fp32 MFMA acc -> logit err ~0.01 (safe).
// SPEC FACT 2: Z = einsum('bhmnd,hdv->bmnd', O, o) is DIAGONAL in d, SUMS v:
//   Z[...,d] = sum_h O_h[...,d] * os[h][d], os[h][d] = sum_v o[h,d,v].
// SPEC FACT 3: S = (A M_h) A_g^T with M_h = q_h k^T. W = A·M_h is group-independent -> big tiled GEMM.
// MFMA conventions (verified r6/r7, absmax 0.125): mfma_f32_16x16x32_f16 computes C = A @ B^T:
//   A-frag: A[m = l16][k = quad*8 + j]; B-frag same over n-rows; C/D: col = l16, row = quad*4 + reg.
#define Bc   8
#define Tc   4096
#define Dc   256
#define EPSc 1e-5f

typedef _Float16 half_t;
typedef __attribute__((ext_vector_type(4))) _Float16 half4_t;
typedef __attribute__((ext_vector_type(8))) _Float16 frag8;
typedef __attribute__((ext_vector_type(4))) float f32x4;

#define MFMA_F16(a, b, c) __builtin_amdgcn_mfma_f32_16x16x32_f16((a), (b), (c), 0, 0, 0)

// ---------------- os[h][d] = sum_v o[h,d,v] ----------------
__global__ __launch_bounds__(256) void osum_kernel(const float* __restrict__ o, float* __restrict__ os) {
  int h = blockIdx.x, d = threadIdx.x;
  const float* row = o + ((size_t)h * 256 + d) * 256;
  float s = 0.f;
  #pragma unroll 8
  for (int v = 0; v < 256; v += 4) {
    float4 r4 = *(const float4*)&row[v];
    s += r4.x + r4.y + r4.z + r4.w;
  }
  os[h * 256 + d] = s;
}

// ---------------- Mt[h][e][d] = M_h[d][e] = sum_i q[h][d][i]*k[e][i]  (f16) ----------------
__global__ __launch_bounds__(256) void prepM_kernel(const float* __restrict__ q,
                                                    const float* __restrict__ k,
                                                    half_t* __restrict__ Mt) {
  __shared__ float shK[64 * 256];
  int h = blockIdx.x >> 2, et = blockIdx.x & 3;
  int tid = threadIdx.x;   // = d
  for (int i = 0; i < 64; i++) shK[i * 256 + tid] = k[(size_t)(et * 64 + i) * 256 + tid];
  __syncthreads();
  const float* qr = q + ((size_t)h * 256 + tid) * 256;
  float acc[64];
  #pragma unroll
  for (int e = 0; e < 64; e++) acc[e] = 0.f;
  for (int i0 = 0; i0 < 256; i0 += 4) {
    float4 qv = *(const float4*)&qr[i0];
    #pragma unroll
    for (int e = 0; e < 64; e++) {
      float4 kv = *(const float4*)&shK[e * 256 + i0];
      acc[e] += qv.x * kv.x + qv.y * kv.y + qv.z * kv.z + qv.w * kv.w;
    }
  }
  for (int e = 0; e < 64; e++)
    Mt[((size_t)h * 256 + et * 64 + e) * 256 + tid] = (half_t)acc[e];
}

// ---------------- transpose v/w1/w2 -> f16 [n][d] ----------------
__global__ __launch_bounds__(256) void prepT_kernel(const float* __restrict__ v,
                                                    const float* __restrict__ w1,
                                                    const float* __restrict__ w2,
                                                    half_t* vt, half_t* w1t, half_t* w2t) {
  int which = blockIdx.x >> 8, n = blockIdx.x & 255, d = threadIdx.x;
  const float* src = which == 0 ? v : (which == 1 ? w1 : w2);
  half_t* dst = which == 0 ? vt : (which == 1 ? w1t : w2t);
  dst[(size_t)n * 256 + d] = (half_t)src[(size_t)d * 256 + n];
}

// ---------------- LN1 + blocked permute -> f16; one wave per row ----------------
__global__ __launch_bounds__(256) void ln1_kernel(
    const float* __restrict__ x, const float* __restrict__ w,
    const float* __restrict__ bia, half_t* __restrict__ aH) {
  int row  = blockIdx.x * 4 + (threadIdx.x >> 6);
  int lane = threadIdx.x & 63;
  float4 v = *(const float4*)&x[(size_t)row * 256 + lane * 4];
  float s  = v.x + v.y + v.z + v.w;
  float sq = v.x * v.x + v.y * v.y + v.z * v.z + v.w * v.w;
  #pragma unroll
  for (int off = 1; off < 64; off <<= 1) { s += __shfl_xor(s, off); sq += __shfl_xor(sq, off); }
  float mean = s * (1.f / 256), var = sq * (1.f / 256) - mean * mean;
  float r = rsqrtf(var + EPSc);
  float4 wv = *(const float4*)&w[lane * 4];
  float4 bv = *(const float4*)&bia[lane * 4];
  half4_t y;
  y[0] = (half_t)((v.x - mean) * r * wv.x + bv.x);
  y[1] = (half_t)((v.y - mean) * r * wv.y + bv.y);
  y[2] = (half_t)((v.z - mean) * r * wv.z + bv.z);
  y[3] = (half_t)((v.w - mean) * r * wv.w + bv.w);
  int bb = row >> 12, p = row & 4095, hh = p >> 6, ww = p & 63;
  int m = (hh & 7) * 8 + (ww & 7), n = (hh >> 3) * 8 + (ww >> 3);
  *(half4_t*)&aH[((size_t)((bb * 64 + m) * 64 + n)) * 256 + lane * 4] = y;
}

// ---------------- tiled GEMM: C(128x128 tile) = A(Mx256) @ Bt(Nx256)^T, K=256 ----------------
// epi 0: -> f16 outh. epi 1: +bias relu -> f16. epi 2: +bias, outf += (resid).
__global__ __launch_bounds__(256) void wgemm_kernel(
    const half_t* __restrict__ A, const half_t* __restrict__ Bt,
    const float* __restrict__ bias, float* __restrict__ outf,
    half_t* __restrict__ outh, int epi, int ldn, int mtiles) {
  __shared__ half_t shA[128 * 72];   // 18 KB, stride 72: 16B-aligned rows, conflict-free
  __shared__ half_t shB[128 * 72];
  int tid = threadIdx.x, lane = tid & 63, wave = tid >> 6;
  int l16 = lane & 15, quad = lane >> 4;
  int mtile = blockIdx.x % mtiles, ntile = blockIdx.x / mtiles;
  int r0 = mtile * 128, n0 = ntile * 128;
  int wm = (wave >> 1) * 64, wn = (wave & 1) * 64;
  f32x4 acc[4][4];
  #pragma unroll
  for (int mt = 0; mt < 4; mt++)
    #pragma unroll
    for (int nt = 0; nt < 4; nt++) acc[mt][nt] = (f32x4){0.f, 0.f, 0.f, 0.f};
  for (int kb = 0; kb < 256; kb += 64) {
    if (kb) __syncthreads();
    #pragma unroll
    for (int rr = 0; rr < 4; rr++) {
      int idx = rr * 256 + tid;
      int row = idx >> 3, c8 = (idx & 7) * 8;
      *(frag8*)&shA[row * 72 + c8] = *(const frag8*)&A[(size_t)(r0 + row) * 256 + kb + c8];
      *(frag8*)&shB[row * 72 + c8] = *(const frag8*)&Bt[(size_t)(n0 + row) * 256 + kb + c8];
    }
    __syncthreads();
    #pragma unroll
    for (int kh = 0; kh < 2; kh++) {
      int ko = kh * 32 + quad * 8;
      frag8 af[4], bf[4];
      #pragma unroll
      for (int mt = 0; mt < 4; mt++) af[mt] = *(const frag8*)&shA[(wm + mt * 16 + l16) * 72 + ko];
      #pragma unroll
      for (int nt = 0; nt < 4; nt++) bf[nt] = *(const frag8*)&shB[(wn + nt * 16 + l16) * 72 + ko];
      #pragma unroll
      for (int mt = 0; mt < 4; mt++)
        #pragma unroll
        for (int nt = 0; nt < 4; nt++) acc[mt][nt] = MFMA_F16(af[mt], bf[nt], acc[mt][nt]);
    }
  }
  #pragma unroll
  for (int mt = 0; mt < 4; mt++)
    #pragma unroll
    for (int nt = 0; nt < 4; nt++)
      #pragma unroll
      for (int r = 0; r < 4; r++) {
        int row = r0 + wm + mt * 16 + quad * 4 + r;
        int col = n0 + wn + nt * 16 + l16;
        float vv = acc[mt][nt][r];
        if (epi) vv += bias[col];
        if (epi == 1) vv = fmaxf(vv, 0.f);
        size_t idx = (size_t)row * ldn + col;
        if (epi == 2) outf[idx] = vv + outf[idx];
        else          outh[idx] = (half_t)vv;
      }
}

// ---------------- fused score+softmax+PV per group, 2 heads (one W chunk) ----------------
// mode 0: group (b, n=slice), tokens over m.  mode 1: group (b, m=slice), tokens over n.
// Wc: [32768][512] f16 (cols = head_sub*256 + e). Z (token space) per-head '='/'+='.
__global__ __launch_bounds__(256) void scorepv_kernel(
    const half_t* __restrict__ aH, const half_t* __restrict__ Wc,
    const half_t* __restrict__ vt, const float* __restrict__ osum,
    half_t* __restrict__ Z, int mode, int hbase, int accum) {
  __shared__ half_t shVT[256 * 72];  // VT_g[d][z], 36.9 KB
  __shared__ half_t shP[64 * 72];    // P[m][z], 9.2 KB
  int tid = threadIdx.x, lane = tid & 63, wave = tid >> 6;
  int l16 = lane & 15, quad = lane >> 4;
  int g = blockIdx.x, b = g >> 6, slice = g & 63;

  // --- in-block vtrans: VT_g[d][z] = sum_e vt[d][e] A_g[z][e]; wave w owns d in [w*64, w*64+64) ---
  {
    f32x4 vacc[4][4];
    #pragma unroll
    for (int dt = 0; dt < 4; dt++)
      #pragma unroll
      for (int zt = 0; zt < 4; zt++) vacc[dt][zt] = (f32x4){0.f, 0.f, 0.f, 0.f};
    for (int ks = 0; ks < 8; ks++) {
      int k0 = ks * 32 + quad * 8;
      frag8 afr[4], bfr[4];
      #pragma unroll
      for (int dt = 0; dt < 4; dt++)
        afr[dt] = *(const frag8*)&vt[(size_t)(wave * 64 + dt * 16 + l16) * 256 + k0];
      #pragma unroll
      for (int zt = 0; zt < 4; zt++) {
        int z = zt * 16 + l16;
        size_t rz = mode ? ((size_t)(b * 64 + slice) * 64 + z) : ((size_t)(b * 64 + z) * 64 + slice);
        bfr[zt] = *(const frag8*)&aH[rz * 256 + k0];
      }
      #pragma unroll
      for (int dt = 0; dt < 4; dt++)
        #pragma unroll
        for (int zt = 0; zt < 4; zt++) vacc[dt][zt] = MFMA_F16(afr[dt], bfr[zt], vacc[dt][zt]);
    }
    #pragma unroll
    for (int dt = 0; dt < 4; dt++)
      #pragma unroll
      for (int zt = 0; zt < 4; zt++)
        #pragma unroll
        for (int r = 0; r < 4; r++)
          shVT[(wave * 64 + dt * 16 + quad * 4 + r) * 72 + zt * 16 + l16] = (half_t)vacc[dt][zt][r];
  }
  __syncthreads();

  for (int hh = 0; hh < 2; hh++) {
    int h = hbase + hh;
    // --- S = W_g,h @ A_g^T : wave = m-quarter (16 rows) ---
    f32x4 sacc[4];
    #pragma unroll
    for (int zt = 0; zt < 4; zt++) sacc[zt] = (f32x4){0.f, 0.f, 0.f, 0.f};
    {
      int m = wave * 16 + l16;
      size_t wrow = mode ? ((size_t)(b * 64 + slice) * 64 + m) : ((size_t)(b * 64 + m) * 64 + slice);
      const half_t* wp = Wc + wrow * 512 + hh * 256;
      for (int ks = 0; ks < 8; ks++) {
        int k0 = ks * 32 + quad * 8;
        frag8 wf = *(const frag8*)&wp[k0];
        #pragma unroll
        for (int zt = 0; zt < 4; zt++) {
          int z = zt * 16 + l16;
          size_t rz = mode ? ((size_t)(b * 64 + slice) * 64 + z) : ((size_t)(b * 64 + z) * 64 + slice);
          frag8 kf = *(const frag8*)&aH[rz * 256 + k0];
          sacc[zt] = MFMA_F16(wf, kf, sacc[zt]);
        }
      }
    }
    // --- softmax rows m = wave*16 + quad*4 + r over 64 z; P -> LDS ---
    #pragma unroll
    for (int r = 0; r < 4; r++) {
      float mx = fmaxf(fmaxf(sacc[0][r], sacc[1][r]), fmaxf(sacc[2][r], sacc[3][r]));
      #pragma unroll
      for (int off = 1; off < 16; off <<= 1) mx = fmaxf(mx, __shfl_xor(mx, off));
      float e0 = __expf(sacc[0][r] - mx), e1 = __expf(sacc[1][r] - mx);
      float e2 = __expf(sacc[2][r] - mx), e3 = __expf(sacc[3][r] - mx);
      float sum = e0 + e1 + e2 + e3;
      #pragma unroll
      for (int off = 1; off < 16; off <<= 1) sum += __shfl_xor(sum, off);
      float inv = 1.f / sum;
      int m = wave * 16 + quad * 4 + r;
      shP[m * 72 + l16 +  0] = (half_t)(e0 * inv);
      shP[m * 72 + l16 + 16] = (half_t)(e1 * inv);
      shP[m * 72 + l16 + 32] = (half_t)(e2 * inv);
      shP[m * 72 + l16 + 48] = (half_t)(e3 * inv);
    }
    __syncthreads();
    // --- PV: O[m][d] = P @ VT^T; Z (+)= O * os[h] ---
    {
      frag8 pf[2];
      #pragma unroll
      for (int ks = 0; ks < 2; ks++)
        pf[ks] = *(const frag8*)&shP[(wave * 16 + l16) * 72 + ks * 32 + quad * 8];
      #pragma unroll
      for (int dt = 0; dt < 16; dt++) {
        f32x4 oacc = (f32x4){0.f, 0.f, 0.f, 0.f};
        #pragma unroll
        for (int ks = 0; ks < 2; ks++) {
          frag8 vf = *(const frag8*)&shVT[(dt * 16 + l16) * 72 + ks * 32 + quad * 8];
          oacc = MFMA_F16(pf[ks], vf, oacc);
        }
        int d = dt * 16 + l16;
        float osv = osum[h * 256 + d];
        #pragma unroll
        for (int r = 0; r < 4; r++) {
          int grow = wave * 16 + quad * 4 + r;
          int mm = mode ? slice : grow;
          int nn = mode ? grow : slice;
          int himg = (nn >> 3) * 8 + (mm >> 3), wimg = (nn & 7) * 8 + (mm & 7);
          size_t zi = ((size_t)(b * 4096 + himg * 64 + wimg)) * 256 + d;
          float val = oacc[r] * osv;
          if (accum || hh) Z[zi] = (half_t)((float)Z[zi] + val);
          else             Z[zi] = (half_t)val;
        }
      }
    }
    __syncthreads();   // protect shP before next head's overwrite
  }
}

// ---------------- residual + LN2; x2 -> d_out fp32, h -> f16 ----------------
__global__ __launch_bounds__(256) void ln2_kernel(
    const float* __restrict__ x, const half_t* __restrict__ Z,
    const float* __restrict__ w, const float* __restrict__ bia,
    float* __restrict__ x2out, half_t* __restrict__ hH) {
  int row  = blockIdx.x * 4 + (threadIdx.x >> 6);
  int lane = threadIdx.x & 63;
  size_t base = (size_t)row * 256 + lane * 4;
  float4 xv = *(const float4*)&x[base];
  half4_t zv = *(const half4_t*)&Z[base];
  float4 v;
  v.x = xv.x + (float)zv[0]; v.y = xv.y + (float)zv[1];
  v.z = xv.z + (float)zv[2]; v.w = xv.w + (float)zv[3];
  float s  = v.x + v.y + v.z + v.w;
  float sq = v.x * v.x + v.y * v.y + v.z * v.z + v.w * v.w;
  #pragma unroll
  for (int off = 1; off < 64; off <<= 1) { s += __shfl_xor(s, off); sq += __shfl_xor(sq, off); }
  float mean = s * (1.f / 256), var = sq * (1.f / 256) - mean * mean;
  float r = rsqrtf(var + EPSc);
  float4 wv = *(const float4*)&w[lane * 4];
  float4 bv = *(const float4*)&bia[lane * 4];
  *(float4*)&x2out[base] = v;
  half4_t y;
  y[0] = (half_t)((v.x - mean) * r * wv.x + bv.x);
  y[1] = (half_t)((v.y - mean) * r * wv.y + bv.y);
  y[2] = (half_t)((v.z - mean) * r * wv.z + bv.z);
  y[3] = (half_t)((v.w - mean) * r * wv.w + bv.w);
  *(half4_t*)&hH[base] = y;
}

extern "C" void kernel_launch(void* const* d_in, const int* in_sizes, int n_in,
                              void* d_out, int out_size, void* d_ws, size_t ws_size,
                              hipStream_t stream) {
  (void)in_sizes; (void)n_in; (void)out_size; (void)ws_size;
  const float* x    = (const float*)d_in[0];
  const float* ln1w = (const float*)d_in[1];
  const float* ln1b = (const float*)d_in[2];
  const float* q    = (const float*)d_in[3];
  const float* k    = (const float*)d_in[4];
  const float* v    = (const float*)d_in[5];
  const float* o    = (const float*)d_in[6];
  const float* ln2w = (const float*)d_in[7];
  const float* ln2b = (const float*)d_in[8];
  const float* w1   = (const float*)d_in[9];
  const float* b1   = (const float*)d_in[10];
  const float* w2   = (const float*)d_in[11];
  const float* b2   = (const float*)d_in[12];
  float* out = (float*)d_out;

  const size_t ROWS = (size_t)Bc * Tc;        // 32768
  const size_t ELTS = ROWS * Dc;              // 8,388,608
  const size_t MB16 = ELTS * sizeof(half_t);  // 16 MiB
  // ws plan (66 MiB total; 82 MiB verified safe in r7):
  //   [0:8K) os | [64K:1M+64K) Mt [h][e][d] | +1M: vt/w1t/w2t (128K each)
  //   [2M:18M)   aH f16 (blocked)  -> reused as hH after attention
  //   [18M:34M)  Z f16 (token space)
  //   [34M:66M)  W chunk f16 [32768][512] (2 heads)  -> reused as tH after attention
  char* ws = (char*)d_ws;
  float*  osumB = (float*)ws;
  half_t* Mt    = (half_t*)(ws + (64 << 10));
  half_t* vt    = (half_t*)(ws + (64 << 10) + (1 << 20));
  half_t* w1t   = (half_t*)(ws + (64 << 10) + (1 << 20) + (128 << 10));
  half_t* w2t   = (half_t*)(ws + (64 << 10) + (1 << 20) + (256 << 10));
  half_t* aH    = (half_t*)(ws + (2 << 20));
  half_t* Zb    = (half_t*)(ws + (2 << 20) + MB16);
  half_t* Wc    = (half_t*)(ws + (2 << 20) + 2 * MB16);
  half_t* hH    = aH;  // reuse (a dead after attention)
  half_t* tH    = Wc;  // reuse (W dead after attention)

  osum_kernel <<<8,   256, 0, stream>>>(o, osumB);
  prepM_kernel<<<32,  256, 0, stream>>>(q, k, Mt);
  prepT_kernel<<<768, 256, 0, stream>>>(v, w1, w2, vt, w1t, w2t);
  ln1_kernel  <<<ROWS / 4, 256, 0, stream>>>(x, ln1w, ln1b, aH);
  // attention in 4 chunks of 2 heads: W = A @ M_pair (big tiled GEMM), then fused score+softmax+PV
  for (int c = 0; c < 4; c++) {
    int hbase = c * 2;                 // heads {2c, 2c+1}; mode = c>>1
    int mode  = c >> 1;
    wgemm_kernel  <<<1024, 256, 0, stream>>>(aH, Mt + (size_t)hbase * 65536,
                                             nullptr, nullptr, Wc, 0, 512, 256);
    scorepv_kernel<<<512,  256, 0, stream>>>(aH, Wc, vt, osumB, Zb, mode, hbase, c > 0);
  }
  // residual + LN2
  ln2_kernel  <<<ROWS / 4, 256, 0, stream>>>(x, Zb, ln2w, ln2b, out, hH);
  // MLP on the tiled GEMM: fc1 relu -> tH; fc2 +bias +resid -> out
  wgemm_kernel<<<512, 256, 0, stream>>>(hH, w1t, b1, nullptr, tH, 1, 256, 256);
  wgemm_kernel<<<512, 256, 0, stream>>>(tH, w2t, b2, out, nullptr, 2, 256, 256);
}